// Round 8
// baseline (378.130 us; speedup 1.0000x reference)
//
#include <hip/hip_runtime.h>

#define LL 8192
#define HH 128

typedef __attribute__((ext_vector_type(8))) short short8v;
typedef __attribute__((ext_vector_type(4))) short short4v;
typedef __attribute__((ext_vector_type(4))) float f32x4;

__device__ inline short f2bf(float f) {
    union { float f; unsigned u; } x; x.f = f;
    unsigned r = (x.u + 0x7fffu + ((x.u >> 16) & 1u)) >> 16;
    return (short)r;
}
__device__ inline short f2bf_trunc(float f) {
    union { float f; unsigned u; } x; x.f = f;
    return (short)(x.u >> 16);
}
__device__ inline float bf2f(short s) {
    union { unsigned u; float f; } x; x.u = ((unsigned)(unsigned short)s) << 16;
    return x.f;
}

// LN of one 128-float LDS row across a full wave (2 elems/lane) -> packed 2xbf16
__device__ inline unsigned ln_pack(const float* rowF, int lane) {
    float2 xv = *(const float2*)&rowF[lane * 2];
    float s = xv.x + xv.y, s2 = xv.x * xv.x + xv.y * xv.y;
#pragma unroll
    for (int off = 32; off >= 1; off >>= 1) {
        s  += __shfl_xor(s,  off, 64);
        s2 += __shfl_xor(s2, off, 64);
    }
    float mu = s * (1.f / 128.f);
    float var = s2 * (1.f / 128.f) - mu * mu;
    float rstd = rsqrtf(var + 1e-5f);
    unsigned lo = (unsigned short)f2bf((xv.x - mu) * rstd);
    unsigned hi = (unsigned short)f2bf((xv.y - mu) * rstd);
    return lo | (hi << 16);
}

// ---------------------------------------------------------------------------
// one repack kernel: conv w -> bf16 [lay][k][o][i]; stacked QKV bf16 (+scale);
// b3; Wff bf16; zero the 8-row halo pads of both nb ping-pong buffers.
// ---------------------------------------------------------------------------
__global__ __launch_bounds__(256) void repack_all(const float* __restrict__ w,
                                                  const float* __restrict__ Wq,
                                                  const float* __restrict__ Wk,
                                                  const float* __restrict__ Wv,
                                                  const float* __restrict__ bq,
                                                  const float* __restrict__ bk,
                                                  const float* __restrict__ bv,
                                                  const float* __restrict__ Wff,
                                                  short* __restrict__ wkb,
                                                  short* __restrict__ wqkvb,
                                                  float* __restrict__ b3,
                                                  short* __restrict__ wffb,
                                                  unsigned* __restrict__ nbA_u,
                                                  unsigned* __restrict__ nbB_u) {
    const float qs = 0.08838834764831845f;
    int idx = blockIdx.x * 256 + threadIdx.x;
    if (idx < 458752) {                       // 4*128*128*7 conv weights
        int k = idx % 7;
        int t = idx / 7;
        int i = t % HH; t /= HH;
        int o = t % HH;
        int lay = t / HH;
        wkb[((lay * 7 + k) * HH + o) * HH + i] = f2bf(w[idx]);
    } else {
        int j = idx - 458752;
        if (j < 49152) {                      // stacked QKV weights
            int t = j >> 14, r = j & 16383;
            float v = (t == 0) ? Wq[r] * qs : (t == 1) ? Wk[r] : Wv[r];
            wqkvb[j] = f2bf(v);
        } else if (j < 49536) {               // stacked biases
            int jj = j - 49152;
            b3[jj] = (jj < 128) ? bq[jj] * qs : (jj < 256) ? bk[jj - 128] : bv[jj - 256];
        } else if (j < 65920) {               // FF weights
            wffb[j - 49536] = f2bf(Wff[j - 49536]);
        } else if (j < 65920 + 2048) {        // nb halo pads
            int p = j - 65920;
            int u = p & 511, which = p >> 9;
            unsigned* base = (which < 2) ? nbA_u : nbB_u;
            base[(which & 1) ? (524800 + u) : u] = 0u;
        }
    }
}

// ---------------------------------------------------------------------------
// init: h = x + pos_encoding (fp32), nb = LN(h) (bf16, padded). 1 wave/row.
// ---------------------------------------------------------------------------
__global__ __launch_bounds__(256) void pos_ln_kernel(const float* __restrict__ x,
                                                     float* __restrict__ h,
                                                     short* __restrict__ nbp) {
    int wave = threadIdx.x >> 6, lane = threadIdx.x & 63;
    int row = blockIdx.x * 4 + wave;
    int i0 = lane * 2;
    float e = (float)i0 * (1.f / 128.f);
    float denom = powf(10000.f, e);
    float ang = (float)row / denom;
    float sv = sinf(ang), cv = cosf(ang);
    float2 xv = *(const float2*)&x[row * HH + i0];
    float h0 = xv.x + sv, h1 = xv.y + cv;
    *(float2*)&h[row * HH + i0] = make_float2(h0, h1);
    float s = h0 + h1, s2 = h0 * h0 + h1 * h1;
#pragma unroll
    for (int off = 32; off >= 1; off >>= 1) {
        s  += __shfl_xor(s,  off, 64);
        s2 += __shfl_xor(s2, off, 64);
    }
    float mu = s * (1.f / 128.f);
    float var = s2 * (1.f / 128.f) - mu * mu;
    float rstd = rsqrtf(var + 1e-5f);
    unsigned lo = (unsigned short)f2bf((h0 - mu) * rstd);
    unsigned hi = (unsigned short)f2bf((h1 - mu) * rstd);
    ((unsigned*)&nbp[row * HH])[lane] = lo | (hi << 16);
}

// ---------------------------------------------------------------------------
// per-layer conv: h += conv(nb_in) + bias (in place), then nb_out = LN(h).
// 512 threads = 8 waves; wave w -> 16 rows x 16 cols (c0 = w*16).
// 16 waves/CU (vs 8 with 4-wave blocks). k-level register double-buffering.
// ---------------------------------------------------------------------------
__global__ __launch_bounds__(512, 4) void conv_ln_kernel(const short* __restrict__ nbp_in,
                                                         const short* __restrict__ wkl,
                                                         const float* __restrict__ bias,
                                                         float* __restrict__ h,
                                                         short* __restrict__ nbp_out) {
    __shared__ float sF[16][132];
    int tid = threadIdx.x;
    int w = tid >> 6, lane = tid & 63;
    int l15 = lane & 15, quad = lane >> 4;
    int m0 = blockIdx.x * 16;
    int c0 = w * 16;

    const short* arb = nbp_in + (m0 + l15 - 3) * HH + quad * 8;
    const short* wbb = wkl + (c0 + l15) * HH + quad * 8;

    f32x4 acc = (f32x4)(0.f);
    short8v a_c[4], b_c[4], a_n[4], b_n[4];
#pragma unroll
    for (int ks = 0; ks < 4; ks++) {
        a_c[ks] = *(const short8v*)&arb[ks * 32];
        b_c[ks] = *(const short8v*)&wbb[ks * 32];
    }
#pragma unroll
    for (int k = 0; k < 7; k++) {
        if (k < 6) {
            const short* an = arb + (k + 1) * HH;
            const short* bn = wbb + (k + 1) * HH * HH;
#pragma unroll
            for (int ks = 0; ks < 4; ks++) {
                a_n[ks] = *(const short8v*)&an[ks * 32];
                b_n[ks] = *(const short8v*)&bn[ks * 32];
            }
        }
#pragma unroll
        for (int ks = 0; ks < 4; ks++)
            acc = __builtin_amdgcn_mfma_f32_16x16x32_bf16(a_c[ks], b_c[ks], acc, 0, 0, 0);
#pragma unroll
        for (int ks = 0; ks < 4; ks++) { a_c[ks] = a_n[ks]; b_c[ks] = b_n[ks]; }
    }
    float bb = bias[c0 + l15];
#pragma unroll
    for (int r = 0; r < 4; r++) {
        int rowL = quad * 4 + r;
        int g = (m0 + rowL) * HH + c0 + l15;
        float z = h[g] + acc[r] + bb;
        h[g] = z;
        sF[rowL][c0 + l15] = z;
    }
    __syncthreads();
#pragma unroll
    for (int rr = 0; rr < 2; rr++) {
        int rowL = w * 2 + rr;
        unsigned packed = ln_pack(&sF[rowL][0], lane);
        ((unsigned*)&nbp_out[(m0 + rowL) * HH])[lane] = packed;
    }
}

// ---------------------------------------------------------------------------
// QKV gemm from LN'd nb. 512 threads = 8 waves, wave -> 16 cols.
// q,k row-major bf16; v transposed [d][L] via per-wave LDS.
// ---------------------------------------------------------------------------
__global__ __launch_bounds__(512, 4) void qkv_kernel(const short* __restrict__ nbp,
                                                     const short* __restrict__ wqkvb,
                                                     const float* __restrict__ b3,
                                                     short* __restrict__ qb,
                                                     short* __restrict__ kb,
                                                     short* __restrict__ vt) {
    __shared__ short sT[8][16][17];
    int tid = threadIdx.x;
    int w = tid >> 6, lane = tid & 63;
    int l15 = lane & 15, quad = lane >> 4;
    int m0 = blockIdx.x * 16;
    int c0 = w * 16;

    short8v af4[4];
#pragma unroll
    for (int ks = 0; ks < 4; ks++)
        af4[ks] = *(const short8v*)&nbp[(m0 + l15) * HH + ks * 32 + quad * 8];

    for (int t = 0; t < 3; t++) {
        f32x4 acc = (f32x4)(0.f);
        const short* b0 = wqkvb + (t * 128 + c0 + l15) * HH + quad * 8;
#pragma unroll
        for (int ks = 0; ks < 4; ks++) {
            short8v bf0 = *(const short8v*)&b0[ks * 32];
            acc = __builtin_amdgcn_mfma_f32_16x16x32_bf16(af4[ks], bf0, acc, 0, 0, 0);
        }
        float bb = b3[t * 128 + c0 + l15];
        if (t < 2) {
            short* o = (t == 0) ? qb : kb;
#pragma unroll
            for (int r = 0; r < 4; r++)
                o[(m0 + quad * 4 + r) * HH + c0 + l15] = f2bf(acc[r] + bb);
        } else {
#pragma unroll
            for (int r = 0; r < 4; r++)
                sT[w][l15][quad * 4 + r] = f2bf(acc[r] + bb);
            asm volatile("s_waitcnt lgkmcnt(0)" ::: "memory");
#pragma unroll
            for (int cc = 0; cc < 4; cc++) {
                int col = cc * 4 + quad;
                vt[(c0 + col) * LL + m0 + l15] = sT[w][col][l15];
            }
        }
    }
}

// ---------------------------------------------------------------------------
// bf16 MFMA flash attention v4: S^T trick (mfma(K,Q)) + kv-permutation sigma
// => PV A-frag is a LOCAL register repack of exp(s) — no LDS P roundtrip,
// no in-loop cross-lane ops. sigma(ks2,q,j)=16*(2ks2+(j>>2))+4q+(j&3) applied
// to both P-pack and V-staging (consistent => dot product unchanged).
// 128 q-rows/block, 64-row KV chunks in LDS, register prefetch, nsplit split-K.
// ---------------------------------------------------------------------------
#define FBN 64

__global__ __launch_bounds__(256, 4) void flash_mfma_kernel(const short* __restrict__ qs,
                                                            const short* __restrict__ ksrc,
                                                            const short* __restrict__ vsrc,
                                                            short* __restrict__ PO,
                                                            float* __restrict__ Pl,
                                                            int segrows) {
    __shared__ short sK[16 * 64 * 8];   // fragment-major, 16 KB
    __shared__ short sV[16 * 64 * 8];   // sigma-permuted fragment-major, 16 KB

    const int tid = threadIdx.x;
    const int w = tid >> 6, lane = tid & 63;
    const int l15 = lane & 15, quad = lane >> 4;
    const int m0 = blockIdx.x * 128;
    const int seg = blockIdx.y;
    const int jbeg = seg * segrows;
    const int nchunk = segrows >> 6;

    const int vdt = 2 * 0 + (w >> 1);  // base; r adds 2r
    const int vks2 = w & 1;

    // Q fragments (used as B operand; A/B frags share register layout)
    short8v qf[2][4];
#pragma unroll
    for (int mt = 0; mt < 2; mt++)
#pragma unroll
        for (int ks = 0; ks < 4; ks++)
            qf[mt][ks] = *(const short8v*)&qs[(m0 + w * 32 + mt * 16 + l15) * HH + ks * 32 + quad * 8];

    float l_r[2] = {0.f, 0.f};
    f32x4 o_acc[2][8];
#pragma unroll
    for (int mt = 0; mt < 2; mt++)
#pragma unroll
        for (int dt = 0; dt < 8; dt++) o_acc[mt][dt] = (f32x4)(0.f);

    // prefetch first chunk: K rows as A-frags; V as sigma-permuted halves
    short8v kr[4];
    short4v vlo[4], vhi[4];
#pragma unroll
    for (int r = 0; r < 4; r++) {
        kr[r] = *(const short8v*)&ksrc[(jbeg + r * 16 + l15) * HH + w * 32 + quad * 8];
        const short* vrow = vsrc + ((2 * r + (w >> 1)) * 16 + l15) * LL + jbeg + vks2 * 32 + quad * 4;
        vlo[r] = *(const short4v*)&vrow[0];
        vhi[r] = *(const short4v*)&vrow[16];
    }

    for (int c = 0; c < nchunk; c++) {
        __syncthreads();
#pragma unroll
        for (int r = 0; r < 4; r++) {
            *(short8v*)&sK[((w + 4 * r) * 64 + lane) * 8] = kr[r];
            short8v vv;
#pragma unroll
            for (int e = 0; e < 4; e++) { vv[e] = vlo[r][e]; vv[4 + e] = vhi[r][e]; }
            *(short8v*)&sV[((w + 4 * r) * 64 + lane) * 8] = vv;
        }
        __syncthreads();
        if (c + 1 < nchunk) {
            const int j1 = jbeg + (c + 1) * FBN;
#pragma unroll
            for (int r = 0; r < 4; r++) {
                kr[r] = *(const short8v*)&ksrc[(j1 + r * 16 + l15) * HH + w * 32 + quad * 8];
                const short* vrow = vsrc + ((2 * r + (w >> 1)) * 16 + l15) * LL + j1 + vks2 * 32 + quad * 4;
                vlo[r] = *(const short4v*)&vrow[0];
                vhi[r] = *(const short4v*)&vrow[16];
            }
        }
        // ---- S^T = K Q^T : C-layout row = kv (quad*4+r), col = q-row (l15) ----
        f32x4 s_acc[2][4];
#pragma unroll
        for (int mt = 0; mt < 2; mt++)
#pragma unroll
            for (int nt = 0; nt < 4; nt++) s_acc[mt][nt] = (f32x4)(0.f);
#pragma unroll
        for (int nt = 0; nt < 4; nt++)
#pragma unroll
            for (int ks = 0; ks < 4; ks++) {
                short8v kf = *(const short8v*)&sK[((nt * 4 + ks) * 64 + lane) * 8];
                s_acc[0][nt] = __builtin_amdgcn_mfma_f32_16x16x32_bf16(kf, qf[0][ks], s_acc[0][nt], 0, 0, 0);
                s_acc[1][nt] = __builtin_amdgcn_mfma_f32_16x16x32_bf16(kf, qf[1][ks], s_acc[1][nt], 0, 0, 0);
            }
        // ---- p = exp(s): per-lane l-sum (lane = q-row), local pf repack ----
        short8v pf[2][2];
#pragma unroll
        for (int mt = 0; mt < 2; mt++) {
            float ls = 0.f;
#pragma unroll
            for (int nt = 0; nt < 4; nt++)
#pragma unroll
                for (int r = 0; r < 4; r++) {
                    float p = __expf(fminf(s_acc[mt][nt][r], 30.f));
                    s_acc[mt][nt][r] = p;
                    ls += p;
                }
            l_r[mt] += ls;
#pragma unroll
            for (int ks2 = 0; ks2 < 2; ks2++)
#pragma unroll
                for (int j = 0; j < 8; j++)
                    pf[mt][ks2][j] = f2bf_trunc(s_acc[mt][2 * ks2 + (j >> 2)][j & 3]);
        }
        // ---- O += P V (sigma-consistent operands) ----
#pragma unroll
        for (int ks2 = 0; ks2 < 2; ks2++)
#pragma unroll
            for (int dt = 0; dt < 8; dt++) {
                short8v vf = *(const short8v*)&sV[((dt * 2 + ks2) * 64 + lane) * 8];
                o_acc[0][dt] = __builtin_amdgcn_mfma_f32_16x16x32_bf16(pf[0][ks2], vf, o_acc[0][dt], 0, 0, 0);
                o_acc[1][dt] = __builtin_amdgcn_mfma_f32_16x16x32_bf16(pf[1][ks2], vf, o_acc[1][dt], 0, 0, 0);
            }
    }
    // ---- finalize l (reduce across quads), write partials ----
#pragma unroll
    for (int mt = 0; mt < 2; mt++) {
        float v = l_r[mt];
        v += __shfl_xor(v, 16, 64);
        v += __shfl_xor(v, 32, 64);
        if (quad == 0)
            Pl[seg * LL + m0 + w * 32 + mt * 16 + l15] = v;
    }
#pragma unroll
    for (int mt = 0; mt < 2; mt++)
#pragma unroll
        for (int dt = 0; dt < 8; dt++)
#pragma unroll
            for (int r = 0; r < 4; r++)
                PO[(size_t)seg * LL * HH + (m0 + w * 32 + mt * 16 + quad * 4 + r) * HH + dt * 16 + l15] =
                    f2bf(o_acc[mt][dt][r]);
}

// ---------------------------------------------------------------------------
// fused attention-merge + residual + LN + FF gemm + relu + residual -> out
// 512 threads = 8 waves; NSPLIT template-unrolled merge.
// ---------------------------------------------------------------------------
template <int NS>
__global__ __launch_bounds__(512, 4) void ff_kernel(const float* __restrict__ hin,
                                                    const short* __restrict__ PO,
                                                    const float* __restrict__ Pl,
                                                    const short* __restrict__ wffb,
                                                    const float* __restrict__ bff,
                                                    float* __restrict__ out) {
    __shared__ float sF[16][132];
    __shared__ short sA[16][136];
    __shared__ float sLi[16];
    int tid = threadIdx.x;
    int w = tid >> 6, lane = tid & 63;
    int l15 = lane & 15, quad = lane >> 4;
    int m0 = blockIdx.x * 16;

    if (tid < 16) {
        float s = 0.f;
#pragma unroll
        for (int seg = 0; seg < NS; seg++) s += Pl[seg * LL + m0 + tid];
        sLi[tid] = 1.f / s;
    }
    // merge: thread -> 4 elems (row = tid>>5, cols (tid&31)*4..)
    {
        int r = tid >> 5, c4 = (tid & 31) << 2;
        const float* hp = &hin[(m0 + r) * HH + c4];
        float4 hv = *(const float4*)hp;
        float s0 = 0.f, s1 = 0.f, s2 = 0.f, s3 = 0.f;
#pragma unroll
        for (int seg = 0; seg < NS; seg++) {
            short4v pv = *(const short4v*)&PO[(size_t)seg * LL * HH + (m0 + r) * HH + c4];
            s0 += bf2f(pv[0]); s1 += bf2f(pv[1]); s2 += bf2f(pv[2]); s3 += bf2f(pv[3]);
        }
        __syncthreads();   // sLi ready
        float li = sLi[r];
        *(float4*)&sF[r][c4] = make_float4(hv.x + s0 * li, hv.y + s1 * li,
                                           hv.z + s2 * li, hv.w + s3 * li);
    }
    __syncthreads();
#pragma unroll
    for (int rr = 0; rr < 2; rr++) {
        int row = w * 2 + rr;
        ((unsigned*)&sA[row][0])[lane] = ln_pack(&sF[row][0], lane);
    }
    __syncthreads();
    int c0 = w * 16;
    f32x4 acc = (f32x4)(0.f);
    const short* b0 = wffb + (c0 + l15) * HH + quad * 8;
#pragma unroll
    for (int ks = 0; ks < 4; ks++) {
        short8v af = *(const short8v*)&sA[l15][ks * 32 + quad * 8];
        short8v bf0 = *(const short8v*)&b0[ks * 32];
        acc = __builtin_amdgcn_mfma_f32_16x16x32_bf16(af, bf0, acc, 0, 0, 0);
    }
    float bb = bff[c0 + l15];
#pragma unroll
    for (int r = 0; r < 4; r++) {
        int lr = quad * 4 + r;
        out[(m0 + lr) * HH + c0 + l15] = fmaxf(acc[r] + bb, 0.f) + sF[lr][c0 + l15];
    }
}

// ---------------------------------------------------------------------------
extern "C" void kernel_launch(void* const* d_in, const int* in_sizes, int n_in,
                              void* d_out, int out_size, void* d_ws, size_t ws_size,
                              hipStream_t stream) {
    const float* x      = (const float*)d_in[0];
    const float* conv_w = (const float*)d_in[1];
    const float* conv_b = (const float*)d_in[2];
    const float* Wq = (const float*)d_in[3];
    const float* bq = (const float*)d_in[4];
    const float* Wk = (const float*)d_in[5];
    const float* bk = (const float*)d_in[6];
    const float* Wv = (const float*)d_in[7];
    const float* bv = (const float*)d_in[8];
    const float* Wff = (const float*)d_in[9];
    const float* bff = (const float*)d_in[10];
    float* out = (float*)d_out;

    char* ws = (char*)d_ws;
    const size_t MB = 1u << 20;
    float* h    = (float*)(ws);                        // 4 MB, alive to end
    short* qb   = (short*)(ws + 4 * MB);               // 2 MB
    short* kb   = (short*)(ws + 6 * MB);               // 2 MB
    short* vt   = (short*)(ws + 8 * MB);               // 2 MB
    float* Pl   = (float*)(ws + 10 * MB);              // <=512 KB
    short* wffb = (short*)(ws + 10 * MB + 524288);     // 32 KB (alive till ff)
    short* PO   = (short*)(ws + 11 * MB);              // 16 or 32 MB bf16 partials
    // dead-before-flash buffers aliased inside the PO span:
    short* nbA_all = (short*)(ws + 11 * MB);
    short* nbB_all = (short*)(ws + 11 * MB + 2621440);
    short* wkb     = (short*)(ws + 16 * MB);
    short* wqkvb   = (short*)(ws + 17 * MB);
    float* b3      = (float*)(ws + 17 * MB + 131072);
    short* nbA = nbA_all + 8 * HH;
    short* nbB = nbB_all + 8 * HH;

    int nsplit = (ws_size >= (size_t)44 * MB) ? 16 : 8;
    int segrows = LL / nsplit;

    repack_all<<<2058, 256, 0, stream>>>(conv_w, Wq, Wk, Wv, bq, bk, bv, Wff,
                                         wkb, wqkvb, b3, wffb,
                                         (unsigned*)nbA_all, (unsigned*)nbB_all);
    pos_ln_kernel<<<LL / 4, 256, 0, stream>>>(x, h, nbA);

    const int KW = 7 * HH * HH;
    conv_ln_kernel<<<LL / 16, 512, 0, stream>>>(nbA, wkb + 0 * KW, conv_b + 0 * HH, h, nbB);
    conv_ln_kernel<<<LL / 16, 512, 0, stream>>>(nbB, wkb + 1 * KW, conv_b + 1 * HH, h, nbA);
    conv_ln_kernel<<<LL / 16, 512, 0, stream>>>(nbA, wkb + 2 * KW, conv_b + 2 * HH, h, nbB);
    conv_ln_kernel<<<LL / 16, 512, 0, stream>>>(nbB, wkb + 3 * KW, conv_b + 3 * HH, h, nbA);

    qkv_kernel<<<LL / 16, 512, 0, stream>>>(nbA, wqkvb, b3, qb, kb, vt);

    flash_mfma_kernel<<<dim3(LL / 128, nsplit), 256, 0, stream>>>(qb, kb, vt, PO, Pl, segrows);

    if (nsplit == 16)
        ff_kernel<16><<<LL / 16, 512, 0, stream>>>(h, PO, Pl, wffb, bff, out);
    else
        ff_kernel<8><<<LL / 16, 512, 0, stream>>>(h, PO, Pl, wffb, bff, out);
}

// Round 9
// 270.720 us; speedup vs baseline: 1.3968x; 1.3968x over previous
//
#include <hip/hip_runtime.h>

#define LL 8192
#define HH 128

typedef __attribute__((ext_vector_type(8))) short short8v;
typedef __attribute__((ext_vector_type(4))) short short4v;
typedef __attribute__((ext_vector_type(4))) float f32x4;

__device__ inline short f2bf(float f) {
    union { float f; unsigned u; } x; x.f = f;
    unsigned r = (x.u + 0x7fffu + ((x.u >> 16) & 1u)) >> 16;
    return (short)r;
}
__device__ inline short f2bf_trunc(float f) {
    union { float f; unsigned u; } x; x.f = f;
    return (short)(x.u >> 16);
}
__device__ inline float bf2f(short s) {
    union { unsigned u; float f; } x; x.u = ((unsigned)(unsigned short)s) << 16;
    return x.f;
}

// LN of one 128-float LDS row across a full wave (2 elems/lane) -> packed 2xbf16
__device__ inline unsigned ln_pack(const float* rowF, int lane) {
    float2 xv = *(const float2*)&rowF[lane * 2];
    float s = xv.x + xv.y, s2 = xv.x * xv.x + xv.y * xv.y;
#pragma unroll
    for (int off = 32; off >= 1; off >>= 1) {
        s  += __shfl_xor(s,  off, 64);
        s2 += __shfl_xor(s2, off, 64);
    }
    float mu = s * (1.f / 128.f);
    float var = s2 * (1.f / 128.f) - mu * mu;
    float rstd = rsqrtf(var + 1e-5f);
    unsigned lo = (unsigned short)f2bf((xv.x - mu) * rstd);
    unsigned hi = (unsigned short)f2bf((xv.y - mu) * rstd);
    return lo | (hi << 16);
}

// ---------------------------------------------------------------------------
// one repack kernel: conv w -> bf16 [lay][k][o][i]; stacked QKV bf16 (+scale);
// b3; Wff bf16; zero the 8-row halo pads of both nb ping-pong buffers.
// ---------------------------------------------------------------------------
__global__ __launch_bounds__(256) void repack_all(const float* __restrict__ w,
                                                  const float* __restrict__ Wq,
                                                  const float* __restrict__ Wk,
                                                  const float* __restrict__ Wv,
                                                  const float* __restrict__ bq,
                                                  const float* __restrict__ bk,
                                                  const float* __restrict__ bv,
                                                  const float* __restrict__ Wff,
                                                  short* __restrict__ wkb,
                                                  short* __restrict__ wqkvb,
                                                  float* __restrict__ b3,
                                                  short* __restrict__ wffb,
                                                  unsigned* __restrict__ nbA_u,
                                                  unsigned* __restrict__ nbB_u) {
    const float qs = 0.08838834764831845f;
    int idx = blockIdx.x * 256 + threadIdx.x;
    if (idx < 458752) {                       // 4*128*128*7 conv weights
        int k = idx % 7;
        int t = idx / 7;
        int i = t % HH; t /= HH;
        int o = t % HH;
        int lay = t / HH;
        wkb[((lay * 7 + k) * HH + o) * HH + i] = f2bf(w[idx]);
    } else {
        int j = idx - 458752;
        if (j < 49152) {                      // stacked QKV weights
            int t = j >> 14, r = j & 16383;
            float v = (t == 0) ? Wq[r] * qs : (t == 1) ? Wk[r] : Wv[r];
            wqkvb[j] = f2bf(v);
        } else if (j < 49536) {               // stacked biases
            int jj = j - 49152;
            b3[jj] = (jj < 128) ? bq[jj] * qs : (jj < 256) ? bk[jj - 128] : bv[jj - 256];
        } else if (j < 65920) {               // FF weights
            wffb[j - 49536] = f2bf(Wff[j - 49536]);
        } else if (j < 65920 + 2048) {        // nb halo pads
            int p = j - 65920;
            int u = p & 511, which = p >> 9;
            unsigned* base = (which < 2) ? nbA_u : nbB_u;
            base[(which & 1) ? (524800 + u) : u] = 0u;
        }
    }
}

// ---------------------------------------------------------------------------
// init: h = x + pos_encoding (fp32), nb = LN(h) (bf16, padded). 1 wave/row.
// ---------------------------------------------------------------------------
__global__ __launch_bounds__(256) void pos_ln_kernel(const float* __restrict__ x,
                                                     float* __restrict__ h,
                                                     short* __restrict__ nbp) {
    int wave = threadIdx.x >> 6, lane = threadIdx.x & 63;
    int row = blockIdx.x * 4 + wave;
    int i0 = lane * 2;
    float e = (float)i0 * (1.f / 128.f);
    float denom = powf(10000.f, e);
    float ang = (float)row / denom;
    float sv = sinf(ang), cv = cosf(ang);
    float2 xv = *(const float2*)&x[row * HH + i0];
    float h0 = xv.x + sv, h1 = xv.y + cv;
    *(float2*)&h[row * HH + i0] = make_float2(h0, h1);
    float s = h0 + h1, s2 = h0 * h0 + h1 * h1;
#pragma unroll
    for (int off = 32; off >= 1; off >>= 1) {
        s  += __shfl_xor(s,  off, 64);
        s2 += __shfl_xor(s2, off, 64);
    }
    float mu = s * (1.f / 128.f);
    float var = s2 * (1.f / 128.f) - mu * mu;
    float rstd = rsqrtf(var + 1e-5f);
    unsigned lo = (unsigned short)f2bf((h0 - mu) * rstd);
    unsigned hi = (unsigned short)f2bf((h1 - mu) * rstd);
    ((unsigned*)&nbp[row * HH])[lane] = lo | (hi << 16);
}

// ---------------------------------------------------------------------------
// per-layer conv: h += conv(nb_in) + bias (in place), then nb_out = LN(h).
// 512 threads = 8 waves; wave w -> 16 rows x 16 cols (c0 = w*16).
// k-level register double-buffering.
// ---------------------------------------------------------------------------
__global__ __launch_bounds__(512, 4) void conv_ln_kernel(const short* __restrict__ nbp_in,
                                                         const short* __restrict__ wkl,
                                                         const float* __restrict__ bias,
                                                         float* __restrict__ h,
                                                         short* __restrict__ nbp_out) {
    __shared__ float sF[16][132];
    int tid = threadIdx.x;
    int w = tid >> 6, lane = tid & 63;
    int l15 = lane & 15, quad = lane >> 4;
    int m0 = blockIdx.x * 16;
    int c0 = w * 16;

    const short* arb = nbp_in + (m0 + l15 - 3) * HH + quad * 8;
    const short* wbb = wkl + (c0 + l15) * HH + quad * 8;

    f32x4 acc = (f32x4)(0.f);
    short8v a_c[4], b_c[4], a_n[4], b_n[4];
#pragma unroll
    for (int ks = 0; ks < 4; ks++) {
        a_c[ks] = *(const short8v*)&arb[ks * 32];
        b_c[ks] = *(const short8v*)&wbb[ks * 32];
    }
#pragma unroll
    for (int k = 0; k < 7; k++) {
        if (k < 6) {
            const short* an = arb + (k + 1) * HH;
            const short* bn = wbb + (k + 1) * HH * HH;
#pragma unroll
            for (int ks = 0; ks < 4; ks++) {
                a_n[ks] = *(const short8v*)&an[ks * 32];
                b_n[ks] = *(const short8v*)&bn[ks * 32];
            }
        }
#pragma unroll
        for (int ks = 0; ks < 4; ks++)
            acc = __builtin_amdgcn_mfma_f32_16x16x32_bf16(a_c[ks], b_c[ks], acc, 0, 0, 0);
#pragma unroll
        for (int ks = 0; ks < 4; ks++) { a_c[ks] = a_n[ks]; b_c[ks] = b_n[ks]; }
    }
    float bb = bias[c0 + l15];
#pragma unroll
    for (int r = 0; r < 4; r++) {
        int rowL = quad * 4 + r;
        int g = (m0 + rowL) * HH + c0 + l15;
        float z = h[g] + acc[r] + bb;
        h[g] = z;
        sF[rowL][c0 + l15] = z;
    }
    __syncthreads();
#pragma unroll
    for (int rr = 0; rr < 2; rr++) {
        int rowL = w * 2 + rr;
        unsigned packed = ln_pack(&sF[rowL][0], lane);
        ((unsigned*)&nbp_out[(m0 + rowL) * HH])[lane] = packed;
    }
}

// ---------------------------------------------------------------------------
// QKV gemm from LN'd nb. 512 threads = 8 waves, wave -> 16 cols.
// q,k row-major bf16; v transposed [d][L] via per-wave LDS.
// ---------------------------------------------------------------------------
__global__ __launch_bounds__(512, 4) void qkv_kernel(const short* __restrict__ nbp,
                                                     const short* __restrict__ wqkvb,
                                                     const float* __restrict__ b3,
                                                     short* __restrict__ qb,
                                                     short* __restrict__ kb,
                                                     short* __restrict__ vt) {
    __shared__ short sT[8][16][17];
    int tid = threadIdx.x;
    int w = tid >> 6, lane = tid & 63;
    int l15 = lane & 15, quad = lane >> 4;
    int m0 = blockIdx.x * 16;
    int c0 = w * 16;

    short8v af4[4];
#pragma unroll
    for (int ks = 0; ks < 4; ks++)
        af4[ks] = *(const short8v*)&nbp[(m0 + l15) * HH + ks * 32 + quad * 8];

    for (int t = 0; t < 3; t++) {
        f32x4 acc = (f32x4)(0.f);
        const short* b0 = wqkvb + (t * 128 + c0 + l15) * HH + quad * 8;
#pragma unroll
        for (int ks = 0; ks < 4; ks++) {
            short8v bf0 = *(const short8v*)&b0[ks * 32];
            acc = __builtin_amdgcn_mfma_f32_16x16x32_bf16(af4[ks], bf0, acc, 0, 0, 0);
        }
        float bb = b3[t * 128 + c0 + l15];
        if (t < 2) {
            short* o = (t == 0) ? qb : kb;
#pragma unroll
            for (int r = 0; r < 4; r++)
                o[(m0 + quad * 4 + r) * HH + c0 + l15] = f2bf(acc[r] + bb);
        } else {
#pragma unroll
            for (int r = 0; r < 4; r++)
                sT[w][l15][quad * 4 + r] = f2bf(acc[r] + bb);
            asm volatile("s_waitcnt lgkmcnt(0)" ::: "memory");
#pragma unroll
            for (int cc = 0; cc < 4; cc++) {
                int col = cc * 4 + quad;
                vt[(c0 + col) * LL + m0 + l15] = sT[w][col][l15];
            }
        }
    }
}

// ---------------------------------------------------------------------------
// bf16 MFMA flash attention v4b: S^T trick (mfma(K,Q)) + kv-permutation sigma
// => PV A-frag is a LOCAL register repack of exp(s) — no LDS P roundtrip,
// no in-loop cross-lane ops. launch_bounds(256,2): ~170 VGPR live (o_acc 64 +
// qf 32 + s_acc 32 + prefetch 32) — (256,4) in R8 spilled to scratch (434 MB
// writes, 2.7x regression). LDS 32 KB; occupancy VGPR-bound at 3 waves/SIMD.
// ---------------------------------------------------------------------------
#define FBN 64

__global__ __launch_bounds__(256, 2) void flash_mfma_kernel(const short* __restrict__ qs,
                                                            const short* __restrict__ ksrc,
                                                            const short* __restrict__ vsrc,
                                                            short* __restrict__ PO,
                                                            float* __restrict__ Pl,
                                                            int segrows) {
    __shared__ short sK[16 * 64 * 8];   // fragment-major, 16 KB
    __shared__ short sV[16 * 64 * 8];   // sigma-permuted fragment-major, 16 KB

    const int tid = threadIdx.x;
    const int w = tid >> 6, lane = tid & 63;
    const int l15 = lane & 15, quad = lane >> 4;
    const int m0 = blockIdx.x * 128;
    const int seg = blockIdx.y;
    const int jbeg = seg * segrows;
    const int nchunk = segrows >> 6;

    const int vks2 = w & 1;

    // Q fragments (used as B operand; A/B frags share register layout)
    short8v qf[2][4];
#pragma unroll
    for (int mt = 0; mt < 2; mt++)
#pragma unroll
        for (int ks = 0; ks < 4; ks++)
            qf[mt][ks] = *(const short8v*)&qs[(m0 + w * 32 + mt * 16 + l15) * HH + ks * 32 + quad * 8];

    float l_r[2] = {0.f, 0.f};
    f32x4 o_acc[2][8];
#pragma unroll
    for (int mt = 0; mt < 2; mt++)
#pragma unroll
        for (int dt = 0; dt < 8; dt++) o_acc[mt][dt] = (f32x4)(0.f);

    // prefetch first chunk: K rows as A-frags; V as sigma-permuted halves
    short8v kr[4];
    short4v vlo[4], vhi[4];
#pragma unroll
    for (int r = 0; r < 4; r++) {
        kr[r] = *(const short8v*)&ksrc[(jbeg + r * 16 + l15) * HH + w * 32 + quad * 8];
        const short* vrow = vsrc + ((2 * r + (w >> 1)) * 16 + l15) * LL + jbeg + vks2 * 32 + quad * 4;
        vlo[r] = *(const short4v*)&vrow[0];
        vhi[r] = *(const short4v*)&vrow[16];
    }

    for (int c = 0; c < nchunk; c++) {
        __syncthreads();
#pragma unroll
        for (int r = 0; r < 4; r++) {
            *(short8v*)&sK[((w + 4 * r) * 64 + lane) * 8] = kr[r];
            short8v vv;
#pragma unroll
            for (int e = 0; e < 4; e++) { vv[e] = vlo[r][e]; vv[4 + e] = vhi[r][e]; }
            *(short8v*)&sV[((w + 4 * r) * 64 + lane) * 8] = vv;
        }
        __syncthreads();
        if (c + 1 < nchunk) {
            const int j1 = jbeg + (c + 1) * FBN;
#pragma unroll
            for (int r = 0; r < 4; r++) {
                kr[r] = *(const short8v*)&ksrc[(j1 + r * 16 + l15) * HH + w * 32 + quad * 8];
                const short* vrow = vsrc + ((2 * r + (w >> 1)) * 16 + l15) * LL + j1 + vks2 * 32 + quad * 4;
                vlo[r] = *(const short4v*)&vrow[0];
                vhi[r] = *(const short4v*)&vrow[16];
            }
        }
        // ---- S^T = K Q^T : C-layout row = kv (quad*4+r), col = q-row (l15) ----
        f32x4 s_acc[2][4];
#pragma unroll
        for (int mt = 0; mt < 2; mt++)
#pragma unroll
            for (int nt = 0; nt < 4; nt++) s_acc[mt][nt] = (f32x4)(0.f);
#pragma unroll
        for (int nt = 0; nt < 4; nt++)
#pragma unroll
            for (int ks = 0; ks < 4; ks++) {
                short8v kf = *(const short8v*)&sK[((nt * 4 + ks) * 64 + lane) * 8];
                s_acc[0][nt] = __builtin_amdgcn_mfma_f32_16x16x32_bf16(kf, qf[0][ks], s_acc[0][nt], 0, 0, 0);
                s_acc[1][nt] = __builtin_amdgcn_mfma_f32_16x16x32_bf16(kf, qf[1][ks], s_acc[1][nt], 0, 0, 0);
            }
        // ---- p = exp(s): per-lane l-sum (lane = q-row), local pf repack ----
#pragma unroll
        for (int mt = 0; mt < 2; mt++) {
            float ls = 0.f;
            short8v pf[2];
#pragma unroll
            for (int nt = 0; nt < 4; nt++)
#pragma unroll
                for (int r = 0; r < 4; r++) {
                    float p = __expf(fminf(s_acc[mt][nt][r], 30.f));
                    ls += p;
                    pf[nt >> 1][((nt & 1) << 2) | r] = f2bf_trunc(p);
                }
            l_r[mt] += ls;
            // ---- O += P V (sigma-consistent operands) ----
#pragma unroll
            for (int ks2 = 0; ks2 < 2; ks2++)
#pragma unroll
                for (int dt = 0; dt < 8; dt++) {
                    short8v vf = *(const short8v*)&sV[((dt * 2 + ks2) * 64 + lane) * 8];
                    o_acc[mt][dt] = __builtin_amdgcn_mfma_f32_16x16x32_bf16(pf[ks2], vf, o_acc[mt][dt], 0, 0, 0);
                }
        }
    }
    // ---- finalize l (reduce across quads), write partials ----
#pragma unroll
    for (int mt = 0; mt < 2; mt++) {
        float v = l_r[mt];
        v += __shfl_xor(v, 16, 64);
        v += __shfl_xor(v, 32, 64);
        if (quad == 0)
            Pl[seg * LL + m0 + w * 32 + mt * 16 + l15] = v;
    }
#pragma unroll
    for (int mt = 0; mt < 2; mt++)
#pragma unroll
        for (int dt = 0; dt < 8; dt++)
#pragma unroll
            for (int r = 0; r < 4; r++)
                PO[(size_t)seg * LL * HH + (m0 + w * 32 + mt * 16 + quad * 4 + r) * HH + dt * 16 + l15] =
                    f2bf(o_acc[mt][dt][r]);
}

// ---------------------------------------------------------------------------
// fused attention-merge + residual + LN + FF gemm + relu + residual -> out
// 512 threads = 8 waves; NSPLIT template-unrolled merge.
// ---------------------------------------------------------------------------
template <int NS>
__global__ __launch_bounds__(512, 4) void ff_kernel(const float* __restrict__ hin,
                                                    const short* __restrict__ PO,
                                                    const float* __restrict__ Pl,
                                                    const short* __restrict__ wffb,
                                                    const float* __restrict__ bff,
                                                    float* __restrict__ out) {
    __shared__ float sF[16][132];
    __shared__ short sA[16][136];
    __shared__ float sLi[16];
    int tid = threadIdx.x;
    int w = tid >> 6, lane = tid & 63;
    int l15 = lane & 15, quad = lane >> 4;
    int m0 = blockIdx.x * 16;

    if (tid < 16) {
        float s = 0.f;
#pragma unroll
        for (int seg = 0; seg < NS; seg++) s += Pl[seg * LL + m0 + tid];
        sLi[tid] = 1.f / s;
    }
    // merge: thread -> 4 elems (row = tid>>5, cols (tid&31)*4..)
    {
        int r = tid >> 5, c4 = (tid & 31) << 2;
        const float* hp = &hin[(m0 + r) * HH + c4];
        float4 hv = *(const float4*)hp;
        float s0 = 0.f, s1 = 0.f, s2 = 0.f, s3 = 0.f;
#pragma unroll
        for (int seg = 0; seg < NS; seg++) {
            short4v pv = *(const short4v*)&PO[(size_t)seg * LL * HH + (m0 + r) * HH + c4];
            s0 += bf2f(pv[0]); s1 += bf2f(pv[1]); s2 += bf2f(pv[2]); s3 += bf2f(pv[3]);
        }
        __syncthreads();   // sLi ready
        float li = sLi[r];
        *(float4*)&sF[r][c4] = make_float4(hv.x + s0 * li, hv.y + s1 * li,
                                           hv.z + s2 * li, hv.w + s3 * li);
    }
    __syncthreads();
#pragma unroll
    for (int rr = 0; rr < 2; rr++) {
        int row = w * 2 + rr;
        ((unsigned*)&sA[row][0])[lane] = ln_pack(&sF[row][0], lane);
    }
    __syncthreads();
    int c0 = w * 16;
    f32x4 acc = (f32x4)(0.f);
    const short* b0 = wffb + (c0 + l15) * HH + quad * 8;
#pragma unroll
    for (int ks = 0; ks < 4; ks++) {
        short8v af = *(const short8v*)&sA[l15][ks * 32 + quad * 8];
        short8v bf0 = *(const short8v*)&b0[ks * 32];
        acc = __builtin_amdgcn_mfma_f32_16x16x32_bf16(af, bf0, acc, 0, 0, 0);
    }
    float bb = bff[c0 + l15];
#pragma unroll
    for (int r = 0; r < 4; r++) {
        int lr = quad * 4 + r;
        out[(m0 + lr) * HH + c0 + l15] = fmaxf(acc[r] + bb, 0.f) + sF[lr][c0 + l15];
    }
}

// ---------------------------------------------------------------------------
extern "C" void kernel_launch(void* const* d_in, const int* in_sizes, int n_in,
                              void* d_out, int out_size, void* d_ws, size_t ws_size,
                              hipStream_t stream) {
    const float* x      = (const float*)d_in[0];
    const float* conv_w = (const float*)d_in[1];
    const float* conv_b = (const float*)d_in[2];
    const float* Wq = (const float*)d_in[3];
    const float* bq = (const float*)d_in[4];
    const float* Wk = (const float*)d_in[5];
    const float* bk = (const float*)d_in[6];
    const float* Wv = (const float*)d_in[7];
    const float* bv = (const float*)d_in[8];
    const float* Wff = (const float*)d_in[9];
    const float* bff = (const float*)d_in[10];
    float* out = (float*)d_out;

    char* ws = (char*)d_ws;
    const size_t MB = 1u << 20;
    float* h    = (float*)(ws);                        // 4 MB, alive to end
    short* qb   = (short*)(ws + 4 * MB);               // 2 MB
    short* kb   = (short*)(ws + 6 * MB);               // 2 MB
    short* vt   = (short*)(ws + 8 * MB);               // 2 MB
    float* Pl   = (float*)(ws + 10 * MB);              // <=512 KB
    short* wffb = (short*)(ws + 10 * MB + 524288);     // 32 KB (alive till ff)
    short* PO   = (short*)(ws + 11 * MB);              // 16 or 32 MB bf16 partials
    // dead-before-flash buffers aliased inside the PO span:
    short* nbA_all = (short*)(ws + 11 * MB);
    short* nbB_all = (short*)(ws + 11 * MB + 2621440);
    short* wkb     = (short*)(ws + 16 * MB);
    short* wqkvb   = (short*)(ws + 17 * MB);
    float* b3      = (float*)(ws + 17 * MB + 131072);
    short* nbA = nbA_all + 8 * HH;
    short* nbB = nbB_all + 8 * HH;

    int nsplit = (ws_size >= (size_t)44 * MB) ? 16 : 8;
    int segrows = LL / nsplit;

    repack_all<<<2058, 256, 0, stream>>>(conv_w, Wq, Wk, Wv, bq, bk, bv, Wff,
                                         wkb, wqkvb, b3, wffb,
                                         (unsigned*)nbA_all, (unsigned*)nbB_all);
    pos_ln_kernel<<<LL / 4, 256, 0, stream>>>(x, h, nbA);

    const int KW = 7 * HH * HH;
    conv_ln_kernel<<<LL / 16, 512, 0, stream>>>(nbA, wkb + 0 * KW, conv_b + 0 * HH, h, nbB);
    conv_ln_kernel<<<LL / 16, 512, 0, stream>>>(nbB, wkb + 1 * KW, conv_b + 1 * HH, h, nbA);
    conv_ln_kernel<<<LL / 16, 512, 0, stream>>>(nbA, wkb + 2 * KW, conv_b + 2 * HH, h, nbB);
    conv_ln_kernel<<<LL / 16, 512, 0, stream>>>(nbB, wkb + 3 * KW, conv_b + 3 * HH, h, nbA);

    qkv_kernel<<<LL / 16, 512, 0, stream>>>(nbA, wqkvb, b3, qb, kb, vt);

    flash_mfma_kernel<<<dim3(LL / 128, nsplit), 256, 0, stream>>>(qb, kb, vt, PO, Pl, segrows);

    if (nsplit == 16)
        ff_kernel<16><<<LL / 16, 512, 0, stream>>>(h, PO, Pl, wffb, bff, out);
    else
        ff_kernel<8><<<LL / 16, 512, 0, stream>>>(h, PO, Pl, wffb, bff, out);
}

// Round 10
// 261.402 us; speedup vs baseline: 1.4465x; 1.0356x over previous
//
#include <hip/hip_runtime.h>

#define LL 8192
#define HH 128

typedef __attribute__((ext_vector_type(8))) short short8v;
typedef __attribute__((ext_vector_type(4))) short short4v;
typedef __attribute__((ext_vector_type(4))) float f32x4;

__device__ inline short f2bf(float f) {
    union { float f; unsigned u; } x; x.f = f;
    unsigned r = (x.u + 0x7fffu + ((x.u >> 16) & 1u)) >> 16;
    return (short)r;
}
__device__ inline short f2bf_trunc(float f) {
    union { float f; unsigned u; } x; x.f = f;
    return (short)(x.u >> 16);
}
__device__ inline float bf2f(short s) {
    union { unsigned u; float f; } x; x.u = ((unsigned)(unsigned short)s) << 16;
    return x.f;
}

// LN of one 128-float LDS row across a full wave (2 elems/lane) -> packed 2xbf16
__device__ inline unsigned ln_pack(const float* rowF, int lane) {
    float2 xv = *(const float2*)&rowF[lane * 2];
    float s = xv.x + xv.y, s2 = xv.x * xv.x + xv.y * xv.y;
#pragma unroll
    for (int off = 32; off >= 1; off >>= 1) {
        s  += __shfl_xor(s,  off, 64);
        s2 += __shfl_xor(s2, off, 64);
    }
    float mu = s * (1.f / 128.f);
    float var = s2 * (1.f / 128.f) - mu * mu;
    float rstd = rsqrtf(var + 1e-5f);
    unsigned lo = (unsigned short)f2bf((xv.x - mu) * rstd);
    unsigned hi = (unsigned short)f2bf((xv.y - mu) * rstd);
    return lo | (hi << 16);
}

// ---------------------------------------------------------------------------
// one repack kernel: conv w -> bf16 [lay][k][o][i]; stacked QKV bf16 (+scale);
// b3; Wff bf16.
// ---------------------------------------------------------------------------
__global__ __launch_bounds__(256) void repack_all(const float* __restrict__ w,
                                                  const float* __restrict__ Wq,
                                                  const float* __restrict__ Wk,
                                                  const float* __restrict__ Wv,
                                                  const float* __restrict__ bq,
                                                  const float* __restrict__ bk,
                                                  const float* __restrict__ bv,
                                                  const float* __restrict__ Wff,
                                                  short* __restrict__ wkb,
                                                  short* __restrict__ wqkvb,
                                                  float* __restrict__ b3,
                                                  short* __restrict__ wffb) {
    const float qs = 0.08838834764831845f;
    int idx = blockIdx.x * 256 + threadIdx.x;
    if (idx < 458752) {                       // 4*128*128*7 conv weights
        int k = idx % 7;
        int t = idx / 7;
        int i = t % HH; t /= HH;
        int o = t % HH;
        int lay = t / HH;
        wkb[((lay * 7 + k) * HH + o) * HH + i] = f2bf(w[idx]);
    } else {
        int j = idx - 458752;
        if (j < 49152) {                      // stacked QKV weights
            int t = j >> 14, r = j & 16383;
            float v = (t == 0) ? Wq[r] * qs : (t == 1) ? Wk[r] : Wv[r];
            wqkvb[j] = f2bf(v);
        } else if (j < 49536) {               // stacked biases
            int jj = j - 49152;
            b3[jj] = (jj < 128) ? bq[jj] * qs : (jj < 256) ? bk[jj - 128] : bv[jj - 256];
        } else if (j < 65920) {               // FF weights
            wffb[j - 49536] = f2bf(Wff[j - 49536]);
        }
    }
}

// ---------------------------------------------------------------------------
// MEGA pre-flash kernel: pos-enc + 4x(LN -> conv K=7 -> residual) + LN -> QKV.
// 512 threads = 8 waves. Block owns 16 core rows; stages 48 (halo 16/side);
// halo recompute: corruption grows 3 rows/layer from window edge, reaching
// rows 0..11 / 36..47 after 4 layers -> core rows 16..31 exact (R5-verified).
// Wave w: cols c0=w*16, 3 m-tiles of 16 rows; B-frags shared across m-tiles.
// LDS ~44 KB -> 3 blocks/CU = 24 waves/CU.
// ---------------------------------------------------------------------------
__global__ __launch_bounds__(512) void conv4qkv_kernel(const float* __restrict__ x,
                                                       const short* __restrict__ wkb,
                                                       const float* __restrict__ conv_b,
                                                       const short* __restrict__ wqkvb,
                                                       const float* __restrict__ b3,
                                                       float* __restrict__ h,
                                                       short* __restrict__ qb,
                                                       short* __restrict__ kb,
                                                       short* __restrict__ vt) {
    __shared__ float sF[48][132];
    __shared__ short sA[54][136];   // rows 0..2 and 51..53 are zero guards
    __shared__ short sT[8][16][17];
    int tid = threadIdx.x;
    int w = tid >> 6, lane = tid & 63;
    int l15 = lane & 15, quad = lane >> 4;
    int m0 = blockIdx.x * 16;
    int c0 = w * 16;

    // ---- stage rows m0-16 .. m0+31 with positional encoding, zero OOB ----
    for (int idx = tid; idx < 48 * 32; idx += 512) {
        int r = idx >> 5, c4 = (idx & 31) << 2;
        int g = m0 - 16 + r;
        float4 val = make_float4(0.f, 0.f, 0.f, 0.f);
        if (g >= 0 && g < LL) {
            val = *(const float4*)&x[g * HH + c4];
#pragma unroll
            for (int j = 0; j < 4; j++) {
                int i = c4 + j;
                float e = (float)(i & ~1) / 128.f;
                float ang = (float)g / powf(10000.f, e);
                float pe = (i & 1) ? cosf(ang) : sinf(ang);
                ((float*)&val)[j] += pe;
            }
        }
        *(float4*)&sF[r][c4] = val;
    }
    // ---- zero sA guard rows {0,1,2,51,52,53} ----
    for (int idx = tid; idx < 6 * 68; idx += 512) {
        int rr = idx / 68, cc = idx % 68;
        int row = (rr < 3) ? rr : 48 + rr;
        ((unsigned*)&sA[row][0])[cc] = 0u;
    }

    // ---- 4 conv layers entirely in LDS ----
    for (int lay = 0; lay < 4; lay++) {
        __syncthreads();
        // LN staged rows 0..47 -> sA[row+3]; 6 rows/wave
#pragma unroll
        for (int rr = 0; rr < 6; rr++) {
            int row = rr * 8 + w;
            int g = m0 - 16 + row;
            unsigned packed = ln_pack(&sF[row][0], lane);
            if (g < 0 || g >= LL) packed = 0u;
            ((unsigned*)&sA[row + 3][0])[lane] = packed;
        }
        __syncthreads();
        f32x4 acc[3];
#pragma unroll
        for (int mt = 0; mt < 3; mt++) acc[mt] = (f32x4)(0.f);
        const short* wl = wkb + lay * 7 * HH * HH;
        for (int k = 0; k < 7; k++) {
            const short* b0 = wl + (k * HH + c0 + l15) * HH + quad * 8;
#pragma unroll
            for (int ks = 0; ks < 4; ks++) {
                short8v bf0 = *(const short8v*)&b0[ks * 32];
#pragma unroll
                for (int mt = 0; mt < 3; mt++) {
                    short8v af = *(const short8v*)&sA[mt * 16 + l15 + k][ks * 32 + quad * 8];
                    acc[mt] = __builtin_amdgcn_mfma_f32_16x16x32_bf16(af, bf0, acc[mt], 0, 0, 0);
                }
            }
        }
        float bb = conv_b[lay * HH + c0 + l15];
#pragma unroll
        for (int mt = 0; mt < 3; mt++)
#pragma unroll
            for (int r = 0; r < 4; r++)
                sF[mt * 16 + quad * 4 + r][c0 + l15] += acc[mt][r] + bb;
    }
    __syncthreads();
    // ---- write conv-stack output (core rows 16..31) ----
    for (int idx = tid; idx < 16 * 32; idx += 512) {
        int r = idx >> 5, c4 = (idx & 31) << 2;
        *(float4*)&h[(m0 + r) * HH + c4] = *(const float4*)&sF[16 + r][c4];
    }
    // ---- LN core rows -> sA[0..15]: 2 rows/wave ----
#pragma unroll
    for (int rr = 0; rr < 2; rr++) {
        int row = rr * 8 + w;
        ((unsigned*)&sA[row][0])[lane] = ln_pack(&sF[16 + row][0], lane);
    }
    __syncthreads();
    // ---- QKV gemms ----
    short8v af4[4];
#pragma unroll
    for (int ks = 0; ks < 4; ks++)
        af4[ks] = *(const short8v*)&sA[l15][ks * 32 + quad * 8];

    for (int t = 0; t < 3; t++) {
        f32x4 acc = (f32x4)(0.f);
        const short* b0 = wqkvb + (t * 128 + c0 + l15) * HH + quad * 8;
#pragma unroll
        for (int ks = 0; ks < 4; ks++) {
            short8v bf0 = *(const short8v*)&b0[ks * 32];
            acc = __builtin_amdgcn_mfma_f32_16x16x32_bf16(af4[ks], bf0, acc, 0, 0, 0);
        }
        float bb = b3[t * 128 + c0 + l15];
        if (t < 2) {
            short* o = (t == 0) ? qb : kb;
#pragma unroll
            for (int r = 0; r < 4; r++)
                o[(m0 + quad * 4 + r) * HH + c0 + l15] = f2bf(acc[r] + bb);
        } else {
#pragma unroll
            for (int r = 0; r < 4; r++)
                sT[w][l15][quad * 4 + r] = f2bf(acc[r] + bb);
            asm volatile("s_waitcnt lgkmcnt(0)" ::: "memory");
#pragma unroll
            for (int cc = 0; cc < 4; cc++) {
                int col = cc * 4 + quad;
                vt[(c0 + col) * LL + m0 + l15] = sT[w][col][l15];
            }
        }
    }
}

// ---------------------------------------------------------------------------
// bf16 MFMA flash attention v5: S^T trick + sigma permutation (R9-verified).
// LDS-pipe relief: K fragments loaded DIRECT from global (16B contiguous,
// L1-resident across the block's 4 waves) — K never touches LDS; V staged in
// LDS (16 KB), PV V-reads hoisted across both m-tiles. LDS instr/chunk/wave:
// 56 (R9) -> 20. (256,2): ~190 regs live, no spill (R8: cap 128 => 434 MB
// scratch, 2.7x regression).
// ---------------------------------------------------------------------------
#define FBN 64

__global__ __launch_bounds__(256, 2) void flash_mfma_kernel(const short* __restrict__ qs,
                                                            const short* __restrict__ ksrc,
                                                            const short* __restrict__ vsrc,
                                                            short* __restrict__ PO,
                                                            float* __restrict__ Pl,
                                                            int segrows) {
    __shared__ short sV[16 * 64 * 8];   // sigma-permuted fragment-major, 16 KB

    const int tid = threadIdx.x;
    const int w = tid >> 6, lane = tid & 63;
    const int l15 = lane & 15, quad = lane >> 4;
    const int m0 = blockIdx.x * 128;
    const int seg = blockIdx.y;
    const int jbeg = seg * segrows;
    const int nchunk = segrows >> 6;
    const int vks2 = w & 1;

    // Q fragments (B operand; A/B frags share register layout)
    short8v qf[2][4];
#pragma unroll
    for (int mt = 0; mt < 2; mt++)
#pragma unroll
        for (int ks = 0; ks < 4; ks++)
            qf[mt][ks] = *(const short8v*)&qs[(m0 + w * 32 + mt * 16 + l15) * HH + ks * 32 + quad * 8];

    float l_r[2] = {0.f, 0.f};
    f32x4 o_acc[2][8];
#pragma unroll
    for (int mt = 0; mt < 2; mt++)
#pragma unroll
        for (int dt = 0; dt < 8; dt++) o_acc[mt][dt] = (f32x4)(0.f);

    // prefetch V chunk 0 (sigma halves)
    short4v vlo[4], vhi[4];
#pragma unroll
    for (int r = 0; r < 4; r++) {
        const short* vrow = vsrc + ((2 * r + (w >> 1)) * 16 + l15) * LL + jbeg + vks2 * 32 + quad * 4;
        vlo[r] = *(const short4v*)&vrow[0];
        vhi[r] = *(const short4v*)&vrow[16];
    }

    for (int c = 0; c < nchunk; c++) {
        const int j0 = jbeg + c * FBN;
        __syncthreads();
#pragma unroll
        for (int r = 0; r < 4; r++) {
            short8v vv;
#pragma unroll
            for (int e = 0; e < 4; e++) { vv[e] = vlo[r][e]; vv[4 + e] = vhi[r][e]; }
            *(short8v*)&sV[((w + 4 * r) * 64 + lane) * 8] = vv;
        }
        __syncthreads();
        if (c + 1 < nchunk) {
            const int j1 = j0 + FBN;
#pragma unroll
            for (int r = 0; r < 4; r++) {
                const short* vrow = vsrc + ((2 * r + (w >> 1)) * 16 + l15) * LL + j1 + vks2 * 32 + quad * 4;
                vlo[r] = *(const short4v*)&vrow[0];
                vhi[r] = *(const short4v*)&vrow[16];
            }
        }
        // ---- S^T = K Q^T, K fragments DIRECT from global (L1-shared) ----
        f32x4 s_acc[2][4];
#pragma unroll
        for (int nt = 0; nt < 4; nt++) {
            const short* krow = ksrc + (j0 + nt * 16 + l15) * HH + quad * 8;
            short8v kf0 = *(const short8v*)&krow[0];
            short8v kf1 = *(const short8v*)&krow[32];
            short8v kf2 = *(const short8v*)&krow[64];
            short8v kf3 = *(const short8v*)&krow[96];
            f32x4 a0 = (f32x4)(0.f), a1 = (f32x4)(0.f);
            a0 = __builtin_amdgcn_mfma_f32_16x16x32_bf16(kf0, qf[0][0], a0, 0, 0, 0);
            a1 = __builtin_amdgcn_mfma_f32_16x16x32_bf16(kf0, qf[1][0], a1, 0, 0, 0);
            a0 = __builtin_amdgcn_mfma_f32_16x16x32_bf16(kf1, qf[0][1], a0, 0, 0, 0);
            a1 = __builtin_amdgcn_mfma_f32_16x16x32_bf16(kf1, qf[1][1], a1, 0, 0, 0);
            a0 = __builtin_amdgcn_mfma_f32_16x16x32_bf16(kf2, qf[0][2], a0, 0, 0, 0);
            a1 = __builtin_amdgcn_mfma_f32_16x16x32_bf16(kf2, qf[1][2], a1, 0, 0, 0);
            a0 = __builtin_amdgcn_mfma_f32_16x16x32_bf16(kf3, qf[0][3], a0, 0, 0, 0);
            a1 = __builtin_amdgcn_mfma_f32_16x16x32_bf16(kf3, qf[1][3], a1, 0, 0, 0);
            s_acc[0][nt] = a0;
            s_acc[1][nt] = a1;
        }
        // ---- p = exp(s): per-lane l-sum (lane = q-row), local pf repack ----
        short8v pf[2][2];
#pragma unroll
        for (int mt = 0; mt < 2; mt++) {
            float ls = 0.f;
#pragma unroll
            for (int nt = 0; nt < 4; nt++)
#pragma unroll
                for (int r = 0; r < 4; r++) {
                    float p = __expf(fminf(s_acc[mt][nt][r], 30.f));
                    ls += p;
                    pf[mt][nt >> 1][((nt & 1) << 2) | r] = f2bf_trunc(p);
                }
            l_r[mt] += ls;
        }
        // ---- O += P V : V-reads hoisted across both m-tiles ----
#pragma unroll
        for (int ks2 = 0; ks2 < 2; ks2++)
#pragma unroll
            for (int dt = 0; dt < 8; dt++) {
                short8v vf = *(const short8v*)&sV[((dt * 2 + ks2) * 64 + lane) * 8];
                o_acc[0][dt] = __builtin_amdgcn_mfma_f32_16x16x32_bf16(pf[0][ks2], vf, o_acc[0][dt], 0, 0, 0);
                o_acc[1][dt] = __builtin_amdgcn_mfma_f32_16x16x32_bf16(pf[1][ks2], vf, o_acc[1][dt], 0, 0, 0);
            }
    }
    // ---- finalize l (reduce across quads), write partials ----
#pragma unroll
    for (int mt = 0; mt < 2; mt++) {
        float v = l_r[mt];
        v += __shfl_xor(v, 16, 64);
        v += __shfl_xor(v, 32, 64);
        if (quad == 0)
            Pl[seg * LL + m0 + w * 32 + mt * 16 + l15] = v;
    }
#pragma unroll
    for (int mt = 0; mt < 2; mt++)
#pragma unroll
        for (int dt = 0; dt < 8; dt++)
#pragma unroll
            for (int r = 0; r < 4; r++)
                PO[(size_t)seg * LL * HH + (m0 + w * 32 + mt * 16 + quad * 4 + r) * HH + dt * 16 + l15] =
                    f2bf(o_acc[mt][dt][r]);
}

// ---------------------------------------------------------------------------
// fused attention-merge + residual + LN + FF gemm + relu + residual -> out
// 512 threads = 8 waves; NSPLIT template-unrolled merge.
// ---------------------------------------------------------------------------
template <int NS>
__global__ __launch_bounds__(512) void ff_kernel(const float* __restrict__ hin,
                                                 const short* __restrict__ PO,
                                                 const float* __restrict__ Pl,
                                                 const short* __restrict__ wffb,
                                                 const float* __restrict__ bff,
                                                 float* __restrict__ out) {
    __shared__ float sF[16][132];
    __shared__ short sA[16][136];
    __shared__ float sLi[16];
    int tid = threadIdx.x;
    int w = tid >> 6, lane = tid & 63;
    int l15 = lane & 15, quad = lane >> 4;
    int m0 = blockIdx.x * 16;

    if (tid < 16) {
        float s = 0.f;
#pragma unroll
        for (int seg = 0; seg < NS; seg++) s += Pl[seg * LL + m0 + tid];
        sLi[tid] = 1.f / s;
    }
    // merge: thread -> 4 elems (row = tid>>5, cols (tid&31)*4..)
    {
        int r = tid >> 5, c4 = (tid & 31) << 2;
        float4 hv = *(const float4*)&hin[(m0 + r) * HH + c4];
        float s0 = 0.f, s1 = 0.f, s2 = 0.f, s3 = 0.f;
#pragma unroll
        for (int seg = 0; seg < NS; seg++) {
            short4v pv = *(const short4v*)&PO[(size_t)seg * LL * HH + (m0 + r) * HH + c4];
            s0 += bf2f(pv[0]); s1 += bf2f(pv[1]); s2 += bf2f(pv[2]); s3 += bf2f(pv[3]);
        }
        __syncthreads();   // sLi ready
        float li = sLi[r];
        *(float4*)&sF[r][c4] = make_float4(hv.x + s0 * li, hv.y + s1 * li,
                                           hv.z + s2 * li, hv.w + s3 * li);
    }
    __syncthreads();
#pragma unroll
    for (int rr = 0; rr < 2; rr++) {
        int row = rr * 8 + w;
        ((unsigned*)&sA[row][0])[lane] = ln_pack(&sF[row][0], lane);
    }
    __syncthreads();
    int c0 = w * 16;
    f32x4 acc = (f32x4)(0.f);
    const short* b0 = wffb + (c0 + l15) * HH + quad * 8;
#pragma unroll
    for (int ks = 0; ks < 4; ks++) {
        short8v af = *(const short8v*)&sA[l15][ks * 32 + quad * 8];
        short8v bf0 = *(const short8v*)&b0[ks * 32];
        acc = __builtin_amdgcn_mfma_f32_16x16x32_bf16(af, bf0, acc, 0, 0, 0);
    }
    float bb = bff[c0 + l15];
#pragma unroll
    for (int r = 0; r < 4; r++) {
        int lr = quad * 4 + r;
        out[(m0 + lr) * HH + c0 + l15] = fmaxf(acc[r] + bb, 0.f) + sF[lr][c0 + l15];
    }
}

// ---------------------------------------------------------------------------
extern "C" void kernel_launch(void* const* d_in, const int* in_sizes, int n_in,
                              void* d_out, int out_size, void* d_ws, size_t ws_size,
                              hipStream_t stream) {
    const float* x      = (const float*)d_in[0];
    const float* conv_w = (const float*)d_in[1];
    const float* conv_b = (const float*)d_in[2];
    const float* Wq = (const float*)d_in[3];
    const float* bq = (const float*)d_in[4];
    const float* Wk = (const float*)d_in[5];
    const float* bk = (const float*)d_in[6];
    const float* Wv = (const float*)d_in[7];
    const float* bv = (const float*)d_in[8];
    const float* Wff = (const float*)d_in[9];
    const float* bff = (const float*)d_in[10];
    float* out = (float*)d_out;

    char* ws = (char*)d_ws;
    const size_t MB = 1u << 20;
    float* h    = (float*)(ws);                        // 4 MB, alive to end
    short* qb   = (short*)(ws + 4 * MB);               // 2 MB
    short* kb   = (short*)(ws + 6 * MB);               // 2 MB
    short* vt   = (short*)(ws + 8 * MB);               // 2 MB
    float* Pl   = (float*)(ws + 10 * MB);              // <=512 KB
    short* wffb = (short*)(ws + 10 * MB + 524288);     // 32 KB (alive till ff)
    short* PO   = (short*)(ws + 11 * MB);              // 16 or 32 MB bf16 partials
    // pre-flash-only buffers aliased inside the PO span (dead before flash):
    short* wkb   = (short*)(ws + 16 * MB);             // 896 KB
    short* wqkvb = (short*)(ws + 17 * MB);             // 96 KB
    float* b3    = (float*)(ws + 17 * MB + 131072);    // 1.5 KB

    int nsplit = (ws_size >= (size_t)44 * MB) ? 16 : 8;
    int segrows = LL / nsplit;

    repack_all<<<2050, 256, 0, stream>>>(conv_w, Wq, Wk, Wv, bq, bk, bv, Wff,
                                         wkb, wqkvb, b3, wffb);

    conv4qkv_kernel<<<LL / 16, 512, 0, stream>>>(x, wkb, conv_b, wqkvb, b3,
                                                 h, qb, kb, vt);

    flash_mfma_kernel<<<dim3(LL / 128, nsplit), 256, 0, stream>>>(qb, kb, vt, PO, Pl, segrows);

    if (nsplit == 16)
        ff_kernel<16><<<LL / 16, 512, 0, stream>>>(h, PO, Pl, wffb, bff, out);
    else
        ff_kernel<8><<<LL / 16, 512, 0, stream>>>(h, PO, Pl, wffb, bff, out);
}